// Round 13
// baseline (204.987 us; speedup 1.0000x reference)
//
#include <hip/hip_runtime.h>
#include <hip/hip_bf16.h>

constexpr int HEADS  = 4;
constexpr int HID    = 64;
constexpr int IN_F   = 128;
constexpr int GROUPS = 64;
constexpr float NEG_SLOPE = 0.2f;
constexpr float EPS_SM    = 1e-16f;

typedef short bf16x8 __attribute__((ext_vector_type(8)));
typedef float f32x4  __attribute__((ext_vector_type(4)));

static __device__ __forceinline__ float lrelu(float x) { return x >= 0.f ? x : NEG_SLOPE * x; }
static __device__ __forceinline__ float elu1(float x)  { return x > 0.f ? x : expm1f(x); }

static __device__ __forceinline__ float bf2f(unsigned int u) {
  union { unsigned int i; float f; } x; x.i = u << 16; return x.f;
}
static __device__ __forceinline__ unsigned short f2bf(float f) {
  union { float f; unsigned int i; } x; x.f = f;
  unsigned int lsb = (x.i >> 16) & 1u;
  x.i += 0x7fffu + lsb;
  return (unsigned short)(x.i >> 16);
}
static __device__ __forceinline__ float sel4(float4 v, int i) {
  return i == 0 ? v.x : (i == 1 ? v.y : (i == 2 ? v.z : v.w));
}

// ---- prep (combined): W1T/W2T hi/lo  +  zero cnt/pooled/cntf/tickets ----
__global__ __launch_bounds__(256) void prep_w_kernel(
    const float* __restrict__ W1, unsigned short* __restrict__ W1Thi, unsigned short* __restrict__ W1Tlo,
    const float* __restrict__ W2, unsigned short* __restrict__ W2Thi, unsigned short* __restrict__ W2Tlo,
    int* __restrict__ cnt, float* __restrict__ pooled, float* __restrict__ cntf,
    int* __restrict__ tickets, int N) {
  const int b = blockIdx.x;
  if (b < 128) {
    const int k = b;                     // 0..127
    const int n = threadIdx.x;           // 0..255
    const float w = W1[(size_t)k * 256 + n];
    const unsigned short hi = f2bf(w);
    W1Thi[(size_t)n * 128 + k] = hi;
    W1Tlo[(size_t)n * 128 + k] = f2bf(w - bf2f(hi));
  } else if (b < 192) {
    const int n = b - 128;               // 0..63
    const int k = threadIdx.x;           // 0..255
    const float w = W2[(size_t)k * 64 + n];
    const unsigned short hi = f2bf(w);
    W2Thi[(size_t)n * 256 + k] = hi;
    W2Tlo[(size_t)n * 256 + k] = f2bf(w - bf2f(hi));
  } else if (b == 192) {
    // zero pooled[64*64], cntf[64], tickets[2]
    for (int i = threadIdx.x; i < GROUPS * 64; i += 256) pooled[i] = 0.f;
    if (threadIdx.x < GROUPS) cntf[threadIdx.x] = 0.f;
    if (threadIdx.x < 2) tickets[threadIdx.x] = 0;
  } else {
    const int i = (b - 193) * 256 + threadIdx.x;
    if (i < N) cnt[i] = 0;
  }
}

// ---- GEMM1 via MFMA (blocks < G1) + histogram-with-rank (blocks >= G1) ----
__global__ __launch_bounds__(512) void gemm1_hist_kernel(
    const float* __restrict__ x,
    const unsigned short* __restrict__ WThi, const unsigned short* __restrict__ WTlo,
    const float* __restrict__ att_s, const float* __restrict__ att_d,
    unsigned short* __restrict__ h1b, float* __restrict__ as1, float* __restrict__ ad1, int N,
    const int* __restrict__ dst, int* __restrict__ cnt, int* __restrict__ rank, int E, int G1) {
  __shared__ unsigned short wl[2][128 * 128];   // [hi/lo][col][k], 16B-chunk swizzled
  const int tid = threadIdx.x;

  if (blockIdx.x >= G1) {                       // --- histogram part ---
    const int e = (blockIdx.x - G1) * 512 + tid;
    if (e < E) rank[e] = atomicAdd(&cnt[dst[e]], 1);
    return;
  }

  const int rowtile = blockIdx.x >> 1;
  const int ch = blockIdx.x & 1;                // column half (cols ch*128 .. +127)

#pragma unroll
  for (int it = 0; it < 8; ++it) {
    const int idx = it * 512 + tid;             // 0..4095
    const unsigned short* srcp = (it < 4) ? WThi : WTlo;
    const int arr = (it < 4) ? 0 : 1;
    const int rem = idx & 2047;
    const int c = rem >> 4;                     // local col 0..127
    const int j = rem & 15;                     // 16B chunk 0..15
    const uint4 v = *reinterpret_cast<const uint4*>(
        &srcp[((size_t)(ch * 128 + c)) * 128 + j * 8]);
    *reinterpret_cast<uint4*>(&wl[arr][c * 128 + ((j ^ (c & 7)) * 8)]) = v;
  }
  __syncthreads();

  const int lane = tid & 63;
  const int wid  = tid >> 6;                    // 0..7
  const int fr = lane & 15;
  const int fg = lane >> 4;
  const int wrow0 = rowtile * 256 + wid * 32;

  f32x4 acc[2][8];
#pragma unroll
  for (int rg = 0; rg < 2; rg++)
#pragma unroll
    for (int n = 0; n < 8; n++) acc[rg][n] = (f32x4){0.f, 0.f, 0.f, 0.f};

#pragma unroll
  for (int ks = 0; ks < 4; ks++) {
    bf16x8 ahi[2], alo[2];
#pragma unroll
    for (int rg = 0; rg < 2; rg++) {
      const int row = wrow0 + rg * 16 + fr;
      float xv[8];
      if (row < N) {
        const float4 a = *reinterpret_cast<const float4*>(&x[(size_t)row * IN_F + ks * 32 + fg * 8]);
        const float4 b = *reinterpret_cast<const float4*>(&x[(size_t)row * IN_F + ks * 32 + fg * 8 + 4]);
        xv[0]=a.x; xv[1]=a.y; xv[2]=a.z; xv[3]=a.w;
        xv[4]=b.x; xv[5]=b.y; xv[6]=b.z; xv[7]=b.w;
      } else {
#pragma unroll
        for (int j = 0; j < 8; j++) xv[j] = 0.f;
      }
#pragma unroll
      for (int j = 0; j < 8; j++) {
        const unsigned short h = f2bf(xv[j]);
        const float r = xv[j] - bf2f(h);
        ahi[rg][j] = (short)h;
        alo[rg][j] = (short)f2bf(r);
      }
    }
#pragma unroll
    for (int n = 0; n < 8; n++) {
      const int c = n * 16 + fr;
      const int slot = (((ks * 4 + fg) ^ (c & 7)) * 8);
      const bf16x8 bhi = *reinterpret_cast<const bf16x8*>(&wl[0][c * 128 + slot]);
      const bf16x8 blo = *reinterpret_cast<const bf16x8*>(&wl[1][c * 128 + slot]);
#pragma unroll
      for (int rg = 0; rg < 2; rg++) {
        acc[rg][n] = __builtin_amdgcn_mfma_f32_16x16x32_bf16(ahi[rg], bhi, acc[rg][n], 0, 0, 0);
        acc[rg][n] = __builtin_amdgcn_mfma_f32_16x16x32_bf16(alo[rg], bhi, acc[rg][n], 0, 0, 0);
        acc[rg][n] = __builtin_amdgcn_mfma_f32_16x16x32_bf16(ahi[rg], blo, acc[rg][n], 0, 0, 0);
      }
    }
  }

  const int colbase = ch * 128;
#pragma unroll
  for (int rg = 0; rg < 2; rg++) {
    float psS[2][4], psD[2][4];
#pragma unroll
    for (int h = 0; h < 2; h++)
#pragma unroll
      for (int r = 0; r < 4; r++) { psS[h][r] = 0.f; psD[h][r] = 0.f; }
#pragma unroll
    for (int n = 0; n < 8; n++) {
      const int col = colbase + n * 16 + fr;
      const float as_ = att_s[col];
      const float ad_ = att_d[col];
      const int h = n >> 2;
#pragma unroll
      for (int r = 0; r < 4; r++) {
        psS[h][r] = fmaf(acc[rg][n][r], as_, psS[h][r]);
        psD[h][r] = fmaf(acc[rg][n][r], ad_, psD[h][r]);
      }
    }
#pragma unroll
    for (int h = 0; h < 2; h++)
#pragma unroll
      for (int r = 0; r < 4; r++)
#pragma unroll
        for (int o = 8; o > 0; o >>= 1) {
          psS[h][r] += __shfl_xor(psS[h][r], o, 64);
          psD[h][r] += __shfl_xor(psD[h][r], o, 64);
        }
    if (fr == 0) {
#pragma unroll
      for (int r = 0; r < 4; r++) {
        const int row = wrow0 + rg * 16 + fg * 4 + r;
        if (row < N) {
#pragma unroll
          for (int h = 0; h < 2; h++) {
            as1[(size_t)row * 4 + ch * 2 + h] = psS[h][r];
            ad1[(size_t)row * 4 + ch * 2 + h] = psD[h][r];
          }
        }
      }
    }
#pragma unroll
    for (int r = 0; r < 4; r++) {
      const int row = wrow0 + rg * 16 + fg * 4 + r;
      if (row < N) {
#pragma unroll
        for (int n = 0; n < 8; n++)
          h1b[(size_t)row * 256 + colbase + n * 16 + fr] = f2bf(acc[rg][n][r]);
      }
    }
  }
}

// ---- merged block-reduce + (last block) bsum scan -> boff ----
__global__ __launch_bounds__(256) void reduce_scan_kernel(
    const int* __restrict__ cnt, int* __restrict__ bsum, int* __restrict__ boff,
    int* __restrict__ ticket, int N, int NB) {
  __shared__ int ws_[4];
  __shared__ int amLast;
  const int t = threadIdx.x;
  const int i = blockIdx.x * 256 + t;
  int v = (i < N) ? cnt[i] : 0;
#pragma unroll
  for (int o = 32; o > 0; o >>= 1) v += __shfl_xor(v, o, 64);
  if ((t & 63) == 0) ws_[t >> 6] = v;
  __syncthreads();
  if (t == 0) {
    const int total = ws_[0] + ws_[1] + ws_[2] + ws_[3];
    atomicExch(&bsum[blockIdx.x], total);     // device-scope store
    __threadfence();
    amLast = (atomicAdd(ticket, 1) == NB - 1);
  }
  __syncthreads();
  if (!amLast) return;
  // single surviving block: exclusive scan of bsum[0..NB)
  __shared__ int sdata[256];
  int bv = (t < NB) ? atomicAdd(&bsum[t], 0) : 0;  // device-scope load
  sdata[t] = bv;
  __syncthreads();
  for (int o = 1; o < 256; o <<= 1) {
    int x = (t >= o) ? sdata[t - o] : 0;
    __syncthreads();
    sdata[t] += x;
    __syncthreads();
  }
  if (t < NB) boff[t] = sdata[t] - bv;   // exclusive; next kernel reads after dispatch boundary
}

__global__ __launch_bounds__(256) void block_scan_kernel(
    const int* __restrict__ cnt, const int* __restrict__ boff,
    int* __restrict__ row_start, int N) {
  __shared__ int sdata[256];
  const int t = threadIdx.x;
  const int i = blockIdx.x * 256 + t;
  int v = (i < N) ? cnt[i] : 0;
  sdata[t] = v;
  __syncthreads();
  for (int o = 1; o < 256; o <<= 1) {
    int x = (t >= o) ? sdata[t - o] : 0;
    __syncthreads();
    sdata[t] += x;
    __syncthreads();
  }
  if (i < N) {
    const int rs = boff[blockIdx.x] + sdata[t] - v;
    row_start[i] = rs;
    if (i == N - 1) row_start[N] = rs + v;
  }
}

// ---- scatter without atomics: position = row_start[dst] + rank ----
__global__ __launch_bounds__(256) void scatter_kernel(
    const int* __restrict__ src, const int* __restrict__ dst,
    const int* __restrict__ row_start, const int* __restrict__ rank,
    int* __restrict__ csr_src, int E) {
  const int e = blockIdx.x * 256 + threadIdx.x;
  if (e < E) {
    const int pos = row_start[dst[e]] + rank[e];
    csr_src[pos] = src[e];
  }
}

// ---- gather1 FUSED: per-chunk lane-parallel weights -> wave LDS stash -> MLP=4 gather ----
__global__ __launch_bounds__(256) void gather1f_kernel(
    const unsigned short* __restrict__ h1b,
    const float* __restrict__ as1, const float* __restrict__ ad1,
    const float* __restrict__ b1, const int* __restrict__ row_start,
    const int* __restrict__ csr_src, unsigned short* __restrict__ hmidb, int N) {
  __shared__ float wbuf[4][256];    // [wave][edge*4 + head]
  __shared__ int   sbuf[4][64];     // [wave][edge]
  const int lane = threadIdx.x & 63;
  const int wv   = threadIdx.x >> 6;
  const int v = blockIdx.x * 4 + wv;
  if (v >= N) return;
  const int hd = lane >> 4;         // head of this lane's 4 channels
  const int rs = row_start[v], re = row_start[v + 1];
  const float4 adv = *reinterpret_cast<const float4*>(&ad1[(size_t)v * 4]);
  const float4 asv = *reinterpret_cast<const float4*>(&as1[(size_t)v * 4]);
  const float wself_hd = __expf(lrelu(sel4(asv, hd) + sel4(adv, hd)));
  const ushort4 sv = reinterpret_cast<const ushort4*>(h1b + (size_t)v * 256)[lane];
  float4 acc;
  acc.x = wself_hd * bf2f(sv.x); acc.y = wself_hd * bf2f(sv.y);
  acc.z = wself_hd * bf2f(sv.z); acc.w = wself_hd * bf2f(sv.w);
  float4 denp = make_float4(0.f, 0.f, 0.f, 0.f);
  const float* adp = reinterpret_cast<const float*>(&adv);

  for (int base = rs; base < re; base += 64) {
    const int cnt = min(64, re - base);
    int s = v;
    float4 w4 = make_float4(0.f, 0.f, 0.f, 0.f);
    if (lane < cnt) {
      s = csr_src[base + lane];
      const float4 av = *reinterpret_cast<const float4*>(&as1[(size_t)s * 4]);
      const float* ap = reinterpret_cast<const float*>(&av);
      float* wp = reinterpret_cast<float*>(&w4);
#pragma unroll
      for (int h = 0; h < HEADS; h++) wp[h] = __expf(lrelu(ap[h] + adp[h]));
      denp.x += w4.x; denp.y += w4.y; denp.z += w4.z; denp.w += w4.w;
    }
    sbuf[wv][lane] = s;
    *reinterpret_cast<float4*>(&wbuf[wv][lane * 4]) = w4;
    const int cntp = (cnt + 3) & ~3;
    for (int j = 0; j < cntp; j += 4) {
      const int s0 = sbuf[wv][j],     s1 = sbuf[wv][j + 1];
      const int s2 = sbuf[wv][j + 2], s3 = sbuf[wv][j + 3];
      const float y0 = wbuf[wv][(j) * 4 + hd];
      const float y1 = wbuf[wv][(j + 1) * 4 + hd];
      const float y2 = wbuf[wv][(j + 2) * 4 + hd];
      const float y3 = wbuf[wv][(j + 3) * 4 + hd];
      const ushort4 f0 = reinterpret_cast<const ushort4*>(h1b + (size_t)s0 * 256)[lane];
      const ushort4 f1 = reinterpret_cast<const ushort4*>(h1b + (size_t)s1 * 256)[lane];
      const ushort4 f2 = reinterpret_cast<const ushort4*>(h1b + (size_t)s2 * 256)[lane];
      const ushort4 f3 = reinterpret_cast<const ushort4*>(h1b + (size_t)s3 * 256)[lane];
      acc.x = fmaf(y0, bf2f(f0.x), acc.x); acc.y = fmaf(y0, bf2f(f0.y), acc.y);
      acc.z = fmaf(y0, bf2f(f0.z), acc.z); acc.w = fmaf(y0, bf2f(f0.w), acc.w);
      acc.x = fmaf(y1, bf2f(f1.x), acc.x); acc.y = fmaf(y1, bf2f(f1.y), acc.y);
      acc.z = fmaf(y1, bf2f(f1.z), acc.z); acc.w = fmaf(y1, bf2f(f1.w), acc.w);
      acc.x = fmaf(y2, bf2f(f2.x), acc.x); acc.y = fmaf(y2, bf2f(f2.y), acc.y);
      acc.z = fmaf(y2, bf2f(f2.z), acc.z); acc.w = fmaf(y2, bf2f(f2.w), acc.w);
      acc.x = fmaf(y3, bf2f(f3.x), acc.x); acc.y = fmaf(y3, bf2f(f3.y), acc.y);
      acc.z = fmaf(y3, bf2f(f3.z), acc.z); acc.w = fmaf(y3, bf2f(f3.w), acc.w);
    }
  }
#pragma unroll
  for (int o = 32; o > 0; o >>= 1) {
    denp.x += __shfl_xor(denp.x, o, 64);
    denp.y += __shfl_xor(denp.y, o, 64);
    denp.z += __shfl_xor(denp.z, o, 64);
    denp.w += __shfl_xor(denp.w, o, 64);
  }
  const float wi = 1.f / (sel4(denp, hd) + wself_hd + EPS_SM);
  const float4 bv = *reinterpret_cast<const float4*>(&b1[lane * 4]);
  ushort4 ov;
  ov.x = f2bf(elu1(acc.x * wi + bv.x));
  ov.y = f2bf(elu1(acc.y * wi + bv.y));
  ov.z = f2bf(elu1(acc.z * wi + bv.z));
  ov.w = f2bf(elu1(acc.w * wi + bv.w));
  reinterpret_cast<ushort4*>(hmidb + (size_t)v * 256)[lane] = ov;
}

// ---- GEMM2 via MFMA: h2b[N,64](bf16) = hmidb(bf16) @ W2(hi/lo LDS) ; fused alpha2 ----
__global__ __launch_bounds__(512) void gemm2_mfma_kernel(
    const unsigned short* __restrict__ A,
    const unsigned short* __restrict__ W2Thi, const unsigned short* __restrict__ W2Tlo,
    const float* __restrict__ att_s, const float* __restrict__ att_d,
    unsigned short* __restrict__ h2b, float* __restrict__ as2, float* __restrict__ ad2, int N) {
  __shared__ unsigned short wl[2][64 * 256];    // [hi/lo][col][k], 16B-chunk swizzled
  const int tid = threadIdx.x;
#pragma unroll
  for (int it = 0; it < 8; ++it) {
    const int idx = it * 512 + tid;             // 0..4095
    const unsigned short* srcp = (it < 4) ? W2Thi : W2Tlo;
    const int arr = (it < 4) ? 0 : 1;
    const int rem = idx & 2047;
    const int c = rem >> 5;                     // col 0..63
    const int j = rem & 31;                     // 16B chunk 0..31
    const uint4 v = *reinterpret_cast<const uint4*>(&srcp[(size_t)c * 256 + j * 8]);
    *reinterpret_cast<uint4*>(&wl[arr][c * 256 + ((j ^ (c & 7)) * 8)]) = v;
  }
  __syncthreads();

  const int lane = tid & 63;
  const int wid  = tid >> 6;                    // 0..7
  const int fr = lane & 15;
  const int fg = lane >> 4;
  const int wrow0 = blockIdx.x * 128 + wid * 16;
  const int myrow = wrow0 + fr;
  const bool rok = myrow < N;

  f32x4 acc[4];
#pragma unroll
  for (int n = 0; n < 4; n++) acc[n] = (f32x4){0.f, 0.f, 0.f, 0.f};

#pragma unroll
  for (int ks = 0; ks < 8; ks++) {
    bf16x8 a;
    if (rok) {
      a = *reinterpret_cast<const bf16x8*>(&A[(size_t)myrow * 256 + ks * 32 + fg * 8]);
    } else {
#pragma unroll
      for (int j = 0; j < 8; j++) a[j] = 0;
    }
#pragma unroll
    for (int n = 0; n < 4; n++) {
      const int c = n * 16 + fr;
      const int slot = (((ks * 4 + fg) ^ (c & 7)) * 8);
      const bf16x8 bhi = *reinterpret_cast<const bf16x8*>(&wl[0][c * 256 + slot]);
      const bf16x8 blo = *reinterpret_cast<const bf16x8*>(&wl[1][c * 256 + slot]);
      acc[n] = __builtin_amdgcn_mfma_f32_16x16x32_bf16(a, bhi, acc[n], 0, 0, 0);
      acc[n] = __builtin_amdgcn_mfma_f32_16x16x32_bf16(a, blo, acc[n], 0, 0, 0);
    }
  }

  float psS[4] = {0.f, 0.f, 0.f, 0.f}, psD[4] = {0.f, 0.f, 0.f, 0.f};
#pragma unroll
  for (int n = 0; n < 4; n++) {
    const int col = n * 16 + fr;
    const float as_ = att_s[col];
    const float ad_ = att_d[col];
#pragma unroll
    for (int r = 0; r < 4; r++) {
      psS[r] = fmaf(acc[n][r], as_, psS[r]);
      psD[r] = fmaf(acc[n][r], ad_, psD[r]);
    }
  }
#pragma unroll
  for (int r = 0; r < 4; r++)
#pragma unroll
    for (int o = 8; o > 0; o >>= 1) {
      psS[r] += __shfl_xor(psS[r], o, 64);
      psD[r] += __shfl_xor(psD[r], o, 64);
    }
  if (fr == 0) {
#pragma unroll
    for (int r = 0; r < 4; r++) {
      const int row = wrow0 + fg * 4 + r;
      if (row < N) { as2[row] = psS[r]; ad2[row] = psD[r]; }
    }
  }
#pragma unroll
  for (int r = 0; r < 4; r++) {
    const int row = wrow0 + fg * 4 + r;
    if (row < N) {
#pragma unroll
      for (int n = 0; n < 4; n++)
        h2b[(size_t)row * 64 + n * 16 + fr] = f2bf(acc[n][r]);
    }
  }
}

// ---- gather2 FUSED: lane-parallel weights -> wave LDS stash -> half-wave MLP=4 gather ----
__global__ __launch_bounds__(256) void gather2f_kernel(
    const unsigned short* __restrict__ h2b,
    const float* __restrict__ as2, const float* __restrict__ ad2,
    const float* __restrict__ b2, const int* __restrict__ row_start,
    const int* __restrict__ csr_src, float* __restrict__ h2, int N) {
  __shared__ float wbuf[4][64];
  __shared__ int   sbuf[4][64];
  const int lane = threadIdx.x & 63;
  const int wv   = threadIdx.x >> 6;
  const int v = blockIdx.x * 4 + wv;
  if (v >= N) return;
  const int half = lane >> 5;
  const int cl = lane & 31;
  const int rs = row_start[v], re = row_start[v + 1];
  const float adv = ad2[v];
  const float wself = __expf(lrelu(as2[v] + adv));
  float ax = 0.f, ay = 0.f;
  if (half == 0) {
    const unsigned int u = reinterpret_cast<const unsigned int*>(h2b + (size_t)v * 64)[cl];
    ax = wself * bf2f(u & 0xffffu);
    ay = wself * bf2f(u >> 16);
  }
  float denp = 0.f;
  for (int base = rs; base < re; base += 64) {
    const int cnt = min(64, re - base);
    int s = v;
    float w = 0.f;
    if (lane < cnt) {
      s = csr_src[base + lane];
      w = __expf(lrelu(as2[s] + adv));
      denp += w;
    }
    sbuf[wv][lane] = s;
    wbuf[wv][lane] = w;
    const int cntp = (cnt + 7) & ~7;
    for (int j = 0; j < cntp; j += 8) {
      const int b0 = j + half;
      const int s0 = sbuf[wv][b0],     s1 = sbuf[wv][b0 + 2];
      const int s2 = sbuf[wv][b0 + 4], s3 = sbuf[wv][b0 + 6];
      const float y0 = wbuf[wv][b0],     y1 = wbuf[wv][b0 + 2];
      const float y2 = wbuf[wv][b0 + 4], y3 = wbuf[wv][b0 + 6];
      const unsigned int f0 = reinterpret_cast<const unsigned int*>(h2b + (size_t)s0 * 64)[cl];
      const unsigned int f1 = reinterpret_cast<const unsigned int*>(h2b + (size_t)s1 * 64)[cl];
      const unsigned int f2 = reinterpret_cast<const unsigned int*>(h2b + (size_t)s2 * 64)[cl];
      const unsigned int f3 = reinterpret_cast<const unsigned int*>(h2b + (size_t)s3 * 64)[cl];
      ax = fmaf(y0, bf2f(f0 & 0xffffu), ax); ay = fmaf(y0, bf2f(f0 >> 16), ay);
      ax = fmaf(y1, bf2f(f1 & 0xffffu), ax); ay = fmaf(y1, bf2f(f1 >> 16), ay);
      ax = fmaf(y2, bf2f(f2 & 0xffffu), ax); ay = fmaf(y2, bf2f(f2 >> 16), ay);
      ax = fmaf(y3, bf2f(f3 & 0xffffu), ax); ay = fmaf(y3, bf2f(f3 >> 16), ay);
    }
  }
#pragma unroll
  for (int o = 32; o > 0; o >>= 1) denp += __shfl_xor(denp, o, 64);
  ax += __shfl_xor(ax, 32, 64);
  ay += __shfl_xor(ay, 32, 64);
  if (half == 0) {
    const float wi = 1.f / (denp + wself + EPS_SM);
    float2 o;
    o.x = elu1(ax * wi + b2[2 * cl]);
    o.y = elu1(ay * wi + b2[2 * cl + 1]);
    reinterpret_cast<float2*>(h2 + (size_t)v * 64)[cl] = o;
  }
}

// ---- mean-pool (MLP=4 row chunks) + last-block classifier ----
__global__ __launch_bounds__(256) void pool_final_kernel(
    const float* __restrict__ h2, const int* __restrict__ batch,
    float* __restrict__ pooled, float* __restrict__ cntf,
    const float* __restrict__ Wc, const float* __restrict__ bc,
    float* __restrict__ out, int* __restrict__ ticket, int N, int NBLK) {
  __shared__ int amLast;
  const int lane = threadIdx.x & 63;
  const int gw = blockIdx.x * 4 + (threadIdx.x >> 6);
  const int s = gw * 64;
  if (s < N) {
    const int e = min(s + 64, N);
    int cur = batch[s];
    float racc = 0.f;
    int rc = 0;
    auto flush = [&](int g) {
      atomicAdd(&pooled[(size_t)cur * 64 + lane], racc);
      if (lane == 0) atomicAdd(&cntf[cur], (float)rc);
      racc = 0.f; rc = 0; cur = g;
    };
    for (int v = s; v < e; v += 4) {
      const int m = min(4, e - v);
      const float r0 = h2[(size_t)v * 64 + lane];
      const float r1 = (m > 1) ? h2[(size_t)(v + 1) * 64 + lane] : 0.f;
      const float r2 = (m > 2) ? h2[(size_t)(v + 2) * 64 + lane] : 0.f;
      const float r3 = (m > 3) ? h2[(size_t)(v + 3) * 64 + lane] : 0.f;
      const int g0 = batch[v];
      const int g1 = (m > 1) ? batch[v + 1] : g0;
      const int g2 = (m > 2) ? batch[v + 2] : g1;
      const int g3 = (m > 3) ? batch[v + 3] : g2;
      if (g0 == cur && g3 == cur) {
        racc += (r0 + r1) + (r2 + r3);
        rc += m;
      } else {
        if (g0 != cur) flush(g0);
        racc += r0; rc++;
        if (m > 1) { if (g1 != cur) flush(g1); racc += r1; rc++; }
        if (m > 2) { if (g2 != cur) flush(g2); racc += r2; rc++; }
        if (m > 3) { if (g3 != cur) flush(g3); racc += r3; rc++; }
      }
    }
    atomicAdd(&pooled[(size_t)cur * 64 + lane], racc);
    if (lane == 0) atomicAdd(&cntf[cur], (float)rc);
  }
  // ticket: every block participates exactly once
  if (threadIdx.x == 0) {
    __threadfence();
    amLast = (atomicAdd(ticket, 1) == NBLK - 1);
  }
  __syncthreads();
  if (!amLast) return;
  // last block: classifier (device-scope atomic loads for coherence)
  const int g = threadIdx.x;
  if (g < GROUPS) {
    float acc = 0.f;
    for (int c = 0; c < 64; c++) {
      const float p = atomicAdd(&pooled[(size_t)g * 64 + c], 0.f);
      acc = fmaf(p, Wc[c], acc);
    }
    const float cnt = fmaxf(atomicAdd(&cntf[g], 0.f), 1.0f);
    out[g] = acc / cnt + bc[0];
  }
}

extern "C" void kernel_launch(void* const* d_in, const int* in_sizes, int n_in,
                              void* d_out, int out_size, void* d_ws, size_t ws_size,
                              hipStream_t stream) {
  const float* x     = (const float*)d_in[0];
  const int*   ei    = (const int*)d_in[1];
  const int*   batch = (const int*)d_in[2];
  const float* W1    = (const float*)d_in[3];
  const float* atts1 = (const float*)d_in[4];
  const float* attd1 = (const float*)d_in[5];
  const float* b1    = (const float*)d_in[6];
  const float* W2    = (const float*)d_in[7];
  const float* atts2 = (const float*)d_in[8];
  const float* attd2 = (const float*)d_in[9];
  const float* b2    = (const float*)d_in[10];
  const float* Wc    = (const float*)d_in[11];
  const float* bc    = (const float*)d_in[12];
  float* out = (float*)d_out;

  const int N = in_sizes[0] / IN_F;   // 50000
  const int E = in_sizes[1] / 2;      // 800000
  const int* src = ei;
  const int* dst = ei + E;
  const int NB = (N + 255) / 256;     // scan blocks
  const int NRT = (N + 255) / 256;    // gemm1 row tiles
  const int G1 = NRT * 2;             // gemm1 blocks in merged dispatch
  const int GH = (E + 511) / 512;     // hist blocks in merged dispatch
  const int NPOOL = ((N + 63) / 64 + 3) / 4;  // pool blocks

  char* ws = (char*)d_ws;
  size_t off = 0;
  auto take = [&](size_t bytes) -> void* {
    void* p = ws + off;
    off = (off + bytes + 255) & ~(size_t)255;
    return p;
  };
  unsigned short* h1b   = (unsigned short*)take((size_t)N * 256 * 2);
  unsigned short* hmidb = (unsigned short*)take((size_t)N * 256 * 2);
  unsigned short* h2b   = (unsigned short*)take((size_t)N * 64 * 2);
  unsigned short* wthi  = (unsigned short*)take((size_t)256 * 128 * 2);
  unsigned short* wtlo  = (unsigned short*)take((size_t)256 * 128 * 2);
  unsigned short* w2thi = (unsigned short*)take((size_t)64 * 256 * 2);
  unsigned short* w2tlo = (unsigned short*)take((size_t)64 * 256 * 2);
  float* as1      = (float*)take((size_t)N * 4 * sizeof(float));
  float* ad1      = (float*)take((size_t)N * 4 * sizeof(float));
  float* as2      = (float*)take((size_t)N * sizeof(float));
  float* ad2      = (float*)take((size_t)N * sizeof(float));
  int*   cnt      = (int*)take((size_t)N * sizeof(int));
  int*   row_start= (int*)take((size_t)(N + 1) * sizeof(int));
  int*   rank     = (int*)take((size_t)E * sizeof(int));
  int*   csr_src  = (int*)take((size_t)E * sizeof(int));
  int*   bsum     = (int*)take((size_t)NB * sizeof(int));
  int*   boff     = (int*)take((size_t)NB * sizeof(int));
  int*   tickets  = (int*)take(2 * sizeof(int));
  float* pooled   = (float*)take((size_t)GROUPS * 64 * sizeof(float));
  float* cntf     = (float*)take((size_t)GROUPS * sizeof(float));
  float* h2       = (float*)take((size_t)N * 64 * sizeof(float));

  // prep: weights split + zero cnt/pooled/cntf/tickets  (no memsets needed)
  prep_w_kernel<<<193 + NB, 256, 0, stream>>>(W1, wthi, wtlo, W2, w2thi, w2tlo,
                                              cnt, pooled, cntf, tickets, N);

  // conv1 linear (MFMA) + fused alpha + edge histogram (merged dispatch)
  gemm1_hist_kernel<<<G1 + GH, 512, 0, stream>>>(x, wthi, wtlo, atts1, attd1,
                                                 h1b, as1, ad1, N, dst, cnt, rank, E, G1);

  // CSR prefix-sum (merged reduce+scan) + atomic-free scatter
  reduce_scan_kernel<<<NB, 256, 0, stream>>>(cnt, bsum, boff, &tickets[0], N, NB);
  block_scan_kernel<<<NB, 256, 0, stream>>>(cnt, boff, row_start, N);
  scatter_kernel<<<(E + 255) / 256, 256, 0, stream>>>(src, dst, row_start, rank, csr_src, E);

  // conv1 aggregate (weights fused in)
  gather1f_kernel<<<(N + 3) / 4, 256, 0, stream>>>(h1b, as1, ad1, b1, row_start, csr_src, hmidb, N);

  // conv2 (MFMA) + aggregate
  gemm2_mfma_kernel<<<(N + 127) / 128, 512, 0, stream>>>(hmidb, w2thi, w2tlo, atts2, attd2, h2b, as2, ad2, N);
  gather2f_kernel<<<(N + 3) / 4, 256, 0, stream>>>(h2b, as2, ad2, b2, row_start, csr_src, h2, N);

  // pooling + fused classifier (last-block ticket)
  pool_final_kernel<<<NPOOL, 256, 0, stream>>>(h2, batch, pooled, cntf, Wc, bc, out,
                                               &tickets[1], N, NPOOL);

  (void)n_in; (void)out_size; (void)ws_size;
}